// Round 1
// baseline (3189.504 us; speedup 1.0000x reference)
//
#include <hip/hip_runtime.h>

typedef short bf16x8 __attribute__((ext_vector_type(8)));
typedef float f32x4 __attribute__((ext_vector_type(4)));

#define LOG2E 1.44269504088896340736f

__device__ __forceinline__ unsigned short f2bf(float x) {
    unsigned u = __builtin_bit_cast(unsigned, x);
    return (unsigned short)((u + 0x7fffu + ((u >> 16) & 1u)) >> 16);
}

// 256 blocks x 512 threads. Block owns 32 batch rows; wave owns 16 hidden
// channels across all 4 gate strips. Persistent loop over 2048 steps.
__global__ __launch_bounds__(512, 2)
void lstm_persist(const float* __restrict__ zP, const float* __restrict__ condP,
                  const float* __restrict__ startP, const float* __restrict__ WihP,
                  const float* __restrict__ WhhP, const float* __restrict__ bihP,
                  const float* __restrict__ bhhP, const float* __restrict__ WoutP,
                  const float* __restrict__ boutP, float* __restrict__ outP)
{
    // h history ring: 8 slots x 32 rows x 128 hidden (bf16), XOR-swizzled rows
    __shared__ unsigned short hist[8 * 32 * 128];   // 64 KiB
    char* const lds = (char*)hist;

    const int tid  = threadIdx.x;
    const int wave = tid >> 6;
    const int lane = tid & 63;
    const int lo   = lane & 15;       // col within fragment
    const int gq   = lane >> 4;       // 0..3
    const int r0   = blockIdx.x * 32; // global batch-row base
    const int hid0 = wave * 16;       // this wave's hidden slice

    // ---- B fragments of W_eff = W_hh + Wx @ W_out  (bf16, registers) ----
    // strip s in {i,f,g,o}: col = s*128 + hid0 + lo ; k = kt*32 + gq*8 + j
    float wx0[4], wx1[4], bias[4];
    bf16x8 bfrag[4][4];
    #pragma unroll
    for (int s = 0; s < 4; ++s) {
        const int col = s * 128 + hid0 + lo;
        wx0[s]  = WihP[col * 39 + 0];
        wx1[s]  = WihP[col * 39 + 1];
        bias[s] = bihP[col] + bhhP[col];
        #pragma unroll
        for (int kt = 0; kt < 4; ++kt) {
            bf16x8 f;
            #pragma unroll
            for (int j = 0; j < 8; ++j) {
                const int k = kt * 32 + gq * 8 + j;
                const float w = WhhP[col * 128 + k]
                              + wx0[s] * WoutP[k] + wx1[s] * WoutP[128 + k];
                f[j] = (short)f2bf(w);
            }
            bfrag[s][kt] = f;
        }
    }

    // ---- W_out B-fragments for the batched output GEMM ----
    bf16x8 wof[4];
    #pragma unroll
    for (int kt = 0; kt < 4; ++kt) {
        bf16x8 f;
        #pragma unroll
        for (int j = 0; j < 8; ++j) {
            const int k = kt * 32 + gq * 8 + j;
            f[j] = (lo < 2) ? (short)f2bf(WoutP[lo * 128 + k]) : (short)0;
        }
        wof[kt] = f;
    }
    const float bo = (lo < 2) ? boutP[lo] : 0.0f;

    // ---- static projection into registers (C-fragment layout) ----
    f32x4 sp[2][4];  // [m-tile][strip], components = r (row = m*16+gq*4+r)
    #pragma unroll
    for (int m = 0; m < 2; ++m)
        #pragma unroll
        for (int s = 0; s < 4; ++s)
            #pragma unroll
            for (int rr = 0; rr < 4; ++rr)
                sp[m][s][rr] = bias[s];

    for (int j = 0; j < 32; ++j) {   // z part
        float w[4];
        #pragma unroll
        for (int s = 0; s < 4; ++s) w[s] = WihP[(s * 128 + hid0 + lo) * 39 + 2 + j];
        #pragma unroll
        for (int m = 0; m < 2; ++m)
            #pragma unroll
            for (int rr = 0; rr < 4; ++rr) {
                const int row = r0 + m * 16 + gq * 4 + rr;
                const float si = zP[row * 32 + j];
                #pragma unroll
                for (int s = 0; s < 4; ++s) sp[m][s][rr] += si * w[s];
            }
    }
    for (int j = 0; j < 4; ++j) {    // condition part
        float w[4];
        #pragma unroll
        for (int s = 0; s < 4; ++s) w[s] = WihP[(s * 128 + hid0 + lo) * 39 + 34 + j];
        #pragma unroll
        for (int m = 0; m < 2; ++m)
            #pragma unroll
            for (int rr = 0; rr < 4; ++rr) {
                const int row = r0 + m * 16 + gq * 4 + rr;
                const float si = condP[row * 4 + j];
                #pragma unroll
                for (int s = 0; s < 4; ++s) sp[m][s][rr] += si * w[s];
            }
    }
    {   // dt term
        #pragma unroll
        for (int s = 0; s < 4; ++s) {
            const float w = 0.05f * WihP[(s * 128 + hid0 + lo) * 39 + 38];
            #pragma unroll
            for (int m = 0; m < 2; ++m)
                #pragma unroll
                for (int rr = 0; rr < 4; ++rr) sp[m][s][rr] += w;
        }
    }

    // ---- LDS offsets (swizzle: byte ^= (row&7)<<4) ----
    int wroff[2][4];
    #pragma unroll
    for (int m = 0; m < 2; ++m)
        #pragma unroll
        for (int rr = 0; rr < 4; ++rr) {
            const int row = m * 16 + gq * 4 + rr;
            wroff[m][rr] = (row * 256 + (hid0 + lo) * 2) ^ ((row & 7) << 4);
        }
    int rdoff[4];   // m=0; m=1 is +4096 (swizzle-safe)
    #pragma unroll
    for (int kt = 0; kt < 4; ++kt)
        rdoff[kt] = (lo * 256 + kt * 64 + gq * 16) ^ ((lo & 7) << 4);
    int xrdoff[4];  // output-GEMM A reads: slot = wave, mt=1 is +4096
    #pragma unroll
    for (int kt = 0; kt < 4; ++kt)
        xrdoff[kt] = ((wave * 32 + lo) * 256 + kt * 64 + gq * 16) ^ ((lo & 7) << 4);

    // ---- LSTM cell state ----
    f32x4 cst[2];
    cst[0] = f32x4{0.f, 0.f, 0.f, 0.f};
    cst[1] = f32x4{0.f, 0.f, 0.f, 0.f};

    // activation tail: gates -> (h bf16 -> LDS), updates c
    auto tail = [&](f32x4 (&acc)[2][4], const int wbase) {
        #pragma unroll
        for (int m = 0; m < 2; ++m) {
            float h[4];
            #pragma unroll
            for (int rr = 0; rr < 4; ++rr) {
                const float ig = acc[m][0][rr], fg = acc[m][1][rr];
                const float gg = acc[m][2][rr], og = acc[m][3][rr];
                const float si = __builtin_amdgcn_rcpf(1.0f + __builtin_amdgcn_exp2f(ig * -LOG2E));
                const float sf = __builtin_amdgcn_rcpf(1.0f + __builtin_amdgcn_exp2f(fg * -LOG2E));
                const float so = __builtin_amdgcn_rcpf(1.0f + __builtin_amdgcn_exp2f(og * -LOG2E));
                const float tg = 1.0f - 2.0f * __builtin_amdgcn_rcpf(1.0f + __builtin_amdgcn_exp2f(gg * (2.0f * LOG2E)));
                const float cn = sf * cst[m][rr] + si * tg;
                cst[m][rr] = cn;
                const float tc = 1.0f - 2.0f * __builtin_amdgcn_rcpf(1.0f + __builtin_amdgcn_exp2f(cn * (2.0f * LOG2E)));
                h[rr] = so * tc;
            }
            unsigned p01, p23;
            asm("v_cvt_pk_bf16_f32 %0, %1, %2" : "=v"(p01) : "v"(h[0]), "v"(h[1]));
            asm("v_cvt_pk_bf16_f32 %0, %1, %2" : "=v"(p23) : "v"(h[2]), "v"(h[3]));
            *(unsigned short*)(lds + wbase + wroff[m][0]) = (unsigned short)(p01 & 0xffffu);
            *(unsigned short*)(lds + wbase + wroff[m][1]) = (unsigned short)(p01 >> 16);
            *(unsigned short*)(lds + wbase + wroff[m][2]) = (unsigned short)(p23 & 0xffffu);
            *(unsigned short*)(lds + wbase + wroff[m][3]) = (unsigned short)(p23 >> 16);
        }
    };

    // ---- step 0: gates = x_start@Wx.T + SP (pure VALU, h0 = c0 = 0) ----
    {
        f32x4 acc0[2][4];
        #pragma unroll
        for (int m = 0; m < 2; ++m)
            #pragma unroll
            for (int s = 0; s < 4; ++s) acc0[m][s] = sp[m][s];
        #pragma unroll
        for (int m = 0; m < 2; ++m)
            #pragma unroll
            for (int rr = 0; rr < 4; ++rr) {
                const int row = r0 + m * 16 + gq * 4 + rr;
                const float x0 = startP[row * 2 + 0];
                const float x1 = startP[row * 2 + 1];
                #pragma unroll
                for (int s = 0; s < 4; ++s)
                    acc0[m][s][rr] += x0 * wx0[s] + x1 * wx1[s];
            }
        tail(acc0, 0);
    }
    // fold bx = Wx@b_out into sp for t >= 1
    #pragma unroll
    for (int s = 0; s < 4; ++s) {
        const float bx = wx0[s] * boutP[0] + wx1[s] * boutP[1];
        #pragma unroll
        for (int m = 0; m < 2; ++m)
            #pragma unroll
            for (int rr = 0; rr < 4; ++rr) sp[m][s][rr] += bx;
    }
    __syncthreads();

    // ---- main recurrence ----
    #pragma unroll 1
    for (int t = 1; t < 2048; ++t) {
        const int rbase = ((t - 1) & 7) * 8192;
        const int wbase = (t & 7) * 8192;

        bf16x8 af[2][4];
        #pragma unroll
        for (int kt = 0; kt < 4; ++kt) {
            af[0][kt] = __builtin_bit_cast(bf16x8, *(const f32x4*)(lds + rbase + rdoff[kt]));
            af[1][kt] = __builtin_bit_cast(bf16x8, *(const f32x4*)(lds + rbase + rdoff[kt] + 4096));
        }
        f32x4 acc[2][4];
        #pragma unroll
        for (int m = 0; m < 2; ++m)
            #pragma unroll
            for (int s = 0; s < 4; ++s) {
                f32x4 a = sp[m][s];
                #pragma unroll
                for (int kt = 0; kt < 4; ++kt)
                    a = __builtin_amdgcn_mfma_f32_16x16x32_bf16(af[m][kt], bfrag[s][kt], a, 0, 0, 0);
                acc[m][s] = a;
            }
        tail(acc, wbase);
        __syncthreads();

        // every 8 steps: batched output GEMM over the full history ring.
        // wave w handles timestep (t-7+w) = slot w, all 32 rows.
        if ((t & 7) == 7) {
            f32x4 xacc[2];
            xacc[0] = f32x4{0.f, 0.f, 0.f, 0.f};
            xacc[1] = f32x4{0.f, 0.f, 0.f, 0.f};
            #pragma unroll
            for (int mt = 0; mt < 2; ++mt)
                #pragma unroll
                for (int kt = 0; kt < 4; ++kt) {
                    const bf16x8 a = __builtin_bit_cast(bf16x8,
                        *(const f32x4*)(lds + xrdoff[kt] + mt * 4096));
                    xacc[mt] = __builtin_amdgcn_mfma_f32_16x16x32_bf16(a, wof[kt], xacc[mt], 0, 0, 0);
                }
            const int tg = t - 7 + wave;
            if (lo < 2) {
                #pragma unroll
                for (int mt = 0; mt < 2; ++mt)
                    #pragma unroll
                    for (int rr = 0; rr < 4; ++rr) {
                        const int row = mt * 16 + gq * 4 + rr;
                        outP[(size_t)(r0 + row) * 4096 + tg * 2 + lo] = xacc[mt][rr] + bo;
                    }
            }
            __syncthreads();
        }
    }
}

extern "C" void kernel_launch(void* const* d_in, const int* in_sizes, int n_in,
                              void* d_out, int out_size, void* d_ws, size_t ws_size,
                              hipStream_t stream) {
    const float* z    = (const float*)d_in[0];
    const float* cond = (const float*)d_in[1];
    const float* strt = (const float*)d_in[2];
    const float* Wih  = (const float*)d_in[3];
    const float* Whh  = (const float*)d_in[4];
    const float* bih  = (const float*)d_in[5];
    const float* bhh  = (const float*)d_in[6];
    const float* Wout = (const float*)d_in[7];
    const float* bout = (const float*)d_in[8];
    float* out = (float*)d_out;

    hipLaunchKernelGGL(lstm_persist, dim3(256), dim3(512), 0, stream,
                       z, cond, strt, Wih, Whh, bih, bhh, Wout, bout, out);
}

// Round 2
// 3130.468 us; speedup vs baseline: 1.0189x; 1.0189x over previous
//
#include <hip/hip_runtime.h>

typedef short bf16x8 __attribute__((ext_vector_type(8)));
typedef float f32x4 __attribute__((ext_vector_type(4)));

#define LOG2E 1.44269504088896340736f

__device__ __forceinline__ unsigned short f2bf(float x) {
    unsigned u = __builtin_bit_cast(unsigned, x);
    return (unsigned short)((u + 0x7fffu + ((u >> 16) & 1u)) >> 16);
}

// 512 blocks x 512 threads (2 blocks/CU). Block owns 16 batch rows; wave owns
// 16 hidden channels across all 4 gate strips. Persistent loop over 2048 steps.
// Gate pre-activations are computed pre-scaled by -log2e (i,f,o) / +2log2e (g)
// so the tail is exp2/rcp + a couple of fma per activation.
__global__ __launch_bounds__(512, 4)
void lstm_persist(const float* __restrict__ zP, const float* __restrict__ condP,
                  const float* __restrict__ startP, const float* __restrict__ WihP,
                  const float* __restrict__ WhhP, const float* __restrict__ bihP,
                  const float* __restrict__ bhhP, const float* __restrict__ WoutP,
                  const float* __restrict__ boutP, float* __restrict__ outP)
{
    // h history ring: 8 slots x 16 rows x 128 hidden (bf16), XOR-swizzled rows
    __shared__ unsigned short hist[8 * 16 * 128];   // 32 KiB
    char* const lds = (char*)hist;

    const int tid  = threadIdx.x;
    const int wave = tid >> 6;
    const int lane = tid & 63;
    const int lo   = lane & 15;       // col within fragment
    const int gq   = lane >> 4;       // 0..3
    const int r0   = blockIdx.x * 16; // global batch-row base
    const int hid0 = wave * 16;       // this wave's hidden slice

    const float K2 = 2.0f * LOG2E;
    const float ss[4] = { -LOG2E, -LOG2E, 2.0f * LOG2E, -LOG2E };

    // ---- B fragments of W' = ss[s]*(W_hh + Wx @ W_out)  (bf16, registers) ----
    // strip s in {i,f,g,o}: col = s*128 + hid0 + lo ; k = kt*32 + gq*8 + j
    float wxs0[4], wxs1[4], bias[4];
    bf16x8 bfrag[4][4];
    #pragma unroll
    for (int s = 0; s < 4; ++s) {
        const int col = s * 128 + hid0 + lo;
        const float wx0 = WihP[col * 39 + 0];
        const float wx1 = WihP[col * 39 + 1];
        wxs0[s] = ss[s] * wx0;
        wxs1[s] = ss[s] * wx1;
        bias[s] = bihP[col] + bhhP[col];
        #pragma unroll
        for (int kt = 0; kt < 4; ++kt) {
            bf16x8 f;
            #pragma unroll
            for (int j = 0; j < 8; ++j) {
                const int k = kt * 32 + gq * 8 + j;
                const float w = WhhP[col * 128 + k]
                              + wx0 * WoutP[k] + wx1 * WoutP[128 + k];
                f[j] = (short)f2bf(ss[s] * w);
            }
            bfrag[s][kt] = f;
        }
    }

    // ---- W_out B-fragments for the batched output GEMM (true domain) ----
    bf16x8 wof[4];
    #pragma unroll
    for (int kt = 0; kt < 4; ++kt) {
        bf16x8 f;
        #pragma unroll
        for (int j = 0; j < 8; ++j) {
            const int k = kt * 32 + gq * 8 + j;
            f[j] = (lo < 2) ? (short)f2bf(WoutP[lo * 128 + k]) : (short)0;
        }
        wof[kt] = f;
    }
    const float bo = (lo < 2) ? boutP[lo] : 0.0f;

    // ---- static projection into registers (C-fragment layout, pre-scaled) ----
    f32x4 sp[4];  // [strip], components = rr (row = gq*4+rr)
    #pragma unroll
    for (int s = 0; s < 4; ++s)
        #pragma unroll
        for (int rr = 0; rr < 4; ++rr)
            sp[s][rr] = bias[s];

    for (int j = 0; j < 32; ++j) {   // z part
        float w[4];
        #pragma unroll
        for (int s = 0; s < 4; ++s) w[s] = WihP[(s * 128 + hid0 + lo) * 39 + 2 + j];
        #pragma unroll
        for (int rr = 0; rr < 4; ++rr) {
            const int row = r0 + gq * 4 + rr;
            const float si = zP[row * 32 + j];
            #pragma unroll
            for (int s = 0; s < 4; ++s) sp[s][rr] += si * w[s];
        }
    }
    for (int j = 0; j < 4; ++j) {    // condition part
        float w[4];
        #pragma unroll
        for (int s = 0; s < 4; ++s) w[s] = WihP[(s * 128 + hid0 + lo) * 39 + 34 + j];
        #pragma unroll
        for (int rr = 0; rr < 4; ++rr) {
            const int row = r0 + gq * 4 + rr;
            const float si = condP[row * 4 + j];
            #pragma unroll
            for (int s = 0; s < 4; ++s) sp[s][rr] += si * w[s];
        }
    }
    #pragma unroll
    for (int s = 0; s < 4; ++s) {    // dt term + scale
        const float w = 0.05f * WihP[(s * 128 + hid0 + lo) * 39 + 38];
        #pragma unroll
        for (int rr = 0; rr < 4; ++rr) sp[s][rr] = ss[s] * (sp[s][rr] + w);
    }

    // ---- LDS offsets (swizzle: byte ^= (row&7)<<4) ----
    int wroff[4];
    #pragma unroll
    for (int rr = 0; rr < 4; ++rr) {
        const int row = gq * 4 + rr;
        wroff[rr] = (row * 256 + (hid0 + lo) * 2) ^ ((row & 7) << 4);
    }
    int rdoff[4];
    #pragma unroll
    for (int kt = 0; kt < 4; ++kt)
        rdoff[kt] = (lo * 256 + kt * 64 + gq * 16) ^ ((lo & 7) << 4);

    // ---- LSTM cell state ----
    f32x4 cst = f32x4{0.f, 0.f, 0.f, 0.f};

    // activation tail: scaled gates -> (h bf16 -> LDS), updates c
    auto tail = [&](f32x4 (&acc)[4], const int wbase) {
        float h[4];
        #pragma unroll
        for (int rr = 0; rr < 4; ++rr) {
            const float si = __builtin_amdgcn_rcpf(1.0f + __builtin_amdgcn_exp2f(acc[0][rr]));
            const float sf = __builtin_amdgcn_rcpf(1.0f + __builtin_amdgcn_exp2f(acc[1][rr]));
            const float rg = __builtin_amdgcn_rcpf(1.0f + __builtin_amdgcn_exp2f(acc[2][rr]));
            const float so = __builtin_amdgcn_rcpf(1.0f + __builtin_amdgcn_exp2f(acc[3][rr]));
            const float tg = __builtin_fmaf(rg, -2.0f, 1.0f);
            const float cn = __builtin_fmaf(sf, cst[rr], si * tg);
            cst[rr] = cn;
            const float rc = __builtin_amdgcn_rcpf(1.0f + __builtin_amdgcn_exp2f(cn * K2));
            const float tc = __builtin_fmaf(rc, -2.0f, 1.0f);
            h[rr] = so * tc;
        }
        unsigned p01, p23;
        asm("v_cvt_pk_bf16_f32 %0, %1, %2" : "=v"(p01) : "v"(h[0]), "v"(h[1]));
        asm("v_cvt_pk_bf16_f32 %0, %1, %2" : "=v"(p23) : "v"(h[2]), "v"(h[3]));
        *(unsigned short*)(lds + wbase + wroff[0]) = (unsigned short)(p01 & 0xffffu);
        *(unsigned short*)(lds + wbase + wroff[1]) = (unsigned short)(p01 >> 16);
        *(unsigned short*)(lds + wbase + wroff[2]) = (unsigned short)(p23 & 0xffffu);
        *(unsigned short*)(lds + wbase + wroff[3]) = (unsigned short)(p23 >> 16);
    };

    // ---- step 0: gates = ss*(x_start@Wx.T) + SP (pure VALU, h0 = c0 = 0) ----
    {
        f32x4 acc0[4];
        #pragma unroll
        for (int s = 0; s < 4; ++s) acc0[s] = sp[s];
        #pragma unroll
        for (int rr = 0; rr < 4; ++rr) {
            const int row = r0 + gq * 4 + rr;
            const float x0 = startP[row * 2 + 0];
            const float x1 = startP[row * 2 + 1];
            #pragma unroll
            for (int s = 0; s < 4; ++s)
                acc0[s][rr] += x0 * wxs0[s] + x1 * wxs1[s];
        }
        tail(acc0, 0);
    }
    // fold bx = ss*(Wx@b_out) into sp for t >= 1
    #pragma unroll
    for (int s = 0; s < 4; ++s) {
        const float bx = wxs0[s] * boutP[0] + wxs1[s] * boutP[1];
        #pragma unroll
        for (int rr = 0; rr < 4; ++rr) sp[s][rr] += bx;
    }
    __syncthreads();

    // ---- main recurrence ----
    #pragma unroll 1
    for (int t = 1; t < 2048; ++t) {
        const int rbase = ((t - 1) & 7) * 4096;
        const int wbase = (t & 7) * 4096;

        bf16x8 af[4];
        #pragma unroll
        for (int kt = 0; kt < 4; ++kt)
            af[kt] = __builtin_bit_cast(bf16x8, *(const f32x4*)(lds + rbase + rdoff[kt]));

        f32x4 acc[4];
        #pragma unroll
        for (int s = 0; s < 4; ++s) {
            f32x4 a = sp[s];
            #pragma unroll
            for (int kt = 0; kt < 4; ++kt)
                a = __builtin_amdgcn_mfma_f32_16x16x32_bf16(af[kt], bfrag[s][kt], a, 0, 0, 0);
            acc[s] = a;
        }
        tail(acc, wbase);
        __syncthreads();

        // every 8 steps: batched output GEMM over the full history ring.
        // wave w handles timestep (t-7+w) = slot w, all 16 rows.
        if ((t & 7) == 7) {
            f32x4 xacc = f32x4{0.f, 0.f, 0.f, 0.f};
            #pragma unroll
            for (int kt = 0; kt < 4; ++kt) {
                const bf16x8 a = __builtin_bit_cast(bf16x8,
                    *(const f32x4*)(lds + wave * 4096 + rdoff[kt]));
                xacc = __builtin_amdgcn_mfma_f32_16x16x32_bf16(a, wof[kt], xacc, 0, 0, 0);
            }
            const int tg = t - 7 + wave;
            if (lo < 2) {
                #pragma unroll
                for (int rr = 0; rr < 4; ++rr) {
                    const int row = gq * 4 + rr;
                    outP[(size_t)(r0 + row) * 4096 + tg * 2 + lo] = xacc[rr] + bo;
                }
            }
            __syncthreads();
        }
    }
}

extern "C" void kernel_launch(void* const* d_in, const int* in_sizes, int n_in,
                              void* d_out, int out_size, void* d_ws, size_t ws_size,
                              hipStream_t stream) {
    const float* z    = (const float*)d_in[0];
    const float* cond = (const float*)d_in[1];
    const float* strt = (const float*)d_in[2];
    const float* Wih  = (const float*)d_in[3];
    const float* Whh  = (const float*)d_in[4];
    const float* bih  = (const float*)d_in[5];
    const float* bhh  = (const float*)d_in[6];
    const float* Wout = (const float*)d_in[7];
    const float* bout = (const float*)d_in[8];
    float* out = (float*)d_out;

    hipLaunchKernelGGL(lstm_persist, dim3(512), dim3(512), 0, stream,
                       z, cond, strt, Wih, Whh, bih, bhh, Wout, bout, out);
}